// Round 6
// baseline (300.650 us; speedup 1.0000x reference)
//
#include <hip/hip_runtime.h>
#include <hip/hip_fp16.h>
#include <math.h>

typedef _Float16 f16;
typedef _Float16 f16x8 __attribute__((ext_vector_type(8)));
typedef _Float16 f16x4 __attribute__((ext_vector_type(4)));
typedef float    f32x4 __attribute__((ext_vector_type(4)));

#define MFMA16(a,b,c) __builtin_amdgcn_mfma_f32_16x16x32_f16(a, b, c, 0, 0, 0)

#define MASKNEG (-6.0e9f)     // additive mask fill (score units)
#define DEADTHR (-1.0e9f)     // row-max below this => fully-masked row
#define LOG2E   1.44269504088896f

// ---------------------------------------------------------------------------
// Kernel 1: QKV projection.  Q is PRE-SCALED by 1/8 (softmax scale folded).
// Q,K natural f16 [8192][512]; V transposed f16 [(h*4+b)*64+d][2048].
// ---------------------------------------------------------------------------
__global__ __launch_bounds__(256) void qkv_gemm(
    const float* __restrict__ x,
    const float* __restrict__ Wq, const float* __restrict__ bq,
    const float* __restrict__ Wk, const float* __restrict__ bk,
    const float* __restrict__ Wv, const float* __restrict__ bv,
    f16* __restrict__ Qws, f16* __restrict__ Kws, f16* __restrict__ Vt)
{
    __shared__ f16 Al[128 * 48];
    __shared__ f16 Wl[64 * 48];

    const int tid = threadIdx.x;
    const int bx  = blockIdx.x;          // 0..23 (3 weights x 8 n-tiles)
    const int m0  = blockIdx.y * 128;
    const int widx = bx >> 3;            // 0=Q 1=K 2=V
    const int n0   = (bx & 7) * 64;

    const float* W    = (widx == 0) ? Wq : (widx == 1) ? Wk : Wv;
    const float* bias = (widx == 0) ? bq : (widx == 1) ? bk : bv;
    const float scl  = (widx == 0) ? 0.125f : 1.0f;

    const int wid = tid >> 6, lane = tid & 63;
    const int g = lane >> 4, c = lane & 15;
    const int wm = (wid >> 1) * 64, wn = (wid & 1) * 32;
    const int sr = tid >> 3, sc = tid & 7;

    f32x4 acc[4][2] = {};

    for (int kk = 0; kk < 512; kk += 32) {
        __syncthreads();
        #pragma unroll
        for (int rr = 0; rr < 4; ++rr) {
            int row = sr + rr * 32;
            float4 v = *(const float4*)&x[(size_t)(m0 + row) * 512 + kk + sc * 4];
            f16x4 h4 = {(f16)v.x, (f16)v.y, (f16)v.z, (f16)v.w};
            *(f16x4*)&Al[row * 48 + sc * 4] = h4;
        }
        #pragma unroll
        for (int rr = 0; rr < 2; ++rr) {
            int row = sr + rr * 32;
            float4 v = *(const float4*)&W[(size_t)(n0 + row) * 512 + kk + sc * 4];
            f16x4 h4 = {(f16)v.x, (f16)v.y, (f16)v.z, (f16)v.w};
            *(f16x4*)&Wl[row * 48 + sc * 4] = h4;
        }
        __syncthreads();

        f16x8 b0 = *(const f16x8*)&Wl[(wn +  0 + c) * 48 + g * 8];
        f16x8 b1 = *(const f16x8*)&Wl[(wn + 16 + c) * 48 + g * 8];
        #pragma unroll
        for (int mf = 0; mf < 4; ++mf) {
            f16x8 a = *(const f16x8*)&Al[(wm + mf * 16 + c) * 48 + g * 8];
            acc[mf][0] = MFMA16(a, b0, acc[mf][0]);
            acc[mf][1] = MFMA16(a, b1, acc[mf][1]);
        }
    }

    #pragma unroll
    for (int nf = 0; nf < 2; ++nf) {
        int cc = n0 + wn + nf * 16 + c;
        float bval = bias[cc];
        #pragma unroll
        for (int mf = 0; mf < 4; ++mf) {
            if (widx < 2) {
                f16* outp = (widx == 0) ? Qws : Kws;
                #pragma unroll
                for (int r = 0; r < 4; ++r) {
                    int mrow = m0 + wm + mf * 16 + g * 4 + r;
                    outp[(size_t)mrow * 512 + cc] = (f16)((acc[mf][nf][r] + bval) * scl);
                }
            } else {
                int h  = n0 >> 6;
                int d  = wn + nf * 16 + c;
                int t0 = m0 + wm + mf * 16 + g * 4;
                int b  = t0 >> 11;
                int ts = t0 & 2047;
                int nn = h * 4 + b;
                f16x4 pk = {(f16)(acc[mf][nf][0] + bval), (f16)(acc[mf][nf][1] + bval),
                            (f16)(acc[mf][nf][2] + bval), (f16)(acc[mf][nf][3] + bval)};
                *(f16x4*)&Vt[((size_t)(nn * 64 + d)) * 2048 + ts] = pk;
            }
        }
    }
}

// ---------------------------------------------------------------------------
// Kernel 1b: per-(n,d) sum of V over t, for the fully-masked-row override.
// ---------------------------------------------------------------------------
__global__ __launch_bounds__(256) void vsum_kernel(
    const f16* __restrict__ Vt, float* __restrict__ Vsum)
{
    const int row  = blockIdx.x * 4 + (threadIdx.x >> 6);
    const int lane = threadIdx.x & 63;
    const f16* p = Vt + (size_t)row * 2048;
    float s = 0.f;
    #pragma unroll
    for (int i = 0; i < 4; ++i) {
        f16x8 v = *(const f16x8*)&p[i * 512 + lane * 8];
        #pragma unroll
        for (int j = 0; j < 8; ++j) s += (float)v[j];
    }
    #pragma unroll
    for (int off = 1; off < 64; off <<= 1) s += __shfl_xor(s, off, 64);
    if (lane == 0) Vsum[row] = s;
}

// ---------------------------------------------------------------------------
// Kernel 2: fused attention, k-PARITY SPLIT for occupancy.
// Block (qt, n, p): chunk pair (qt, 31-qt), tiles kt ≡ p (mod 2).
//   Every block: exactly 16 tiles (staged parity-subset of [0,32-qt) +
//   score-only parity-subset of [32-qt,32)) and 16-17 live sub-chunks.
// Emits per-row partials (m, l, unnormalized o as f16) to `part`;
// combine_kernel merges the two parities.
// Pl is single-chunk (lo processed, then hi) -> LDS 35.8KB, 4 blocks/CU.
// ---------------------------------------------------------------------------
__global__ __launch_bounds__(256, 3) void attn_kernel(
    const f16* __restrict__ Qws, const f16* __restrict__ Kws,
    const f16* __restrict__ Vt,  const int* __restrict__ pmask,
    float* __restrict__ pre_score, f16* __restrict__ part)
{
    __shared__ f16 Kl[64 * 72];        // [t][d]
    __shared__ f16 Vl[64 * 72];        // [d][t]
    __shared__ f16 Pl[4][16 * 72];     // per-wave [q][k], reused lo->hi
    __shared__ float Bias[2048];       // additive padding-mask bias

    const int tid = threadIdx.x;
    const int wid = tid >> 6, lane = tid & 63;
    const int g = lane >> 4, c = lane & 15;
    const int qt = blockIdx.x;         // 0..15
    const int n  = blockIdx.y;         // 0..31  (= h*4 + b)
    const int p  = blockIdx.z;         // k-tile parity 0/1
    const int h = n >> 2, b = n & 3;
    const int pmrow = n >> 3;          // the reference's ordering quirk
    const int qlo = qt * 64 + wid * 16;
    const int qhi = (31 - qt) * 64 + wid * 16;
    const int qrel = wid * 16 + c;     // in-tile causal threshold

    // --- padding mask -> additive bias in LDS ---
    {
        const int i0 = tid * 8;
        const int4* p4 = (const int4*)(pmask + pmrow * 2048 + i0);
        int4 m0 = p4[0], m1 = p4[1];
        Bias[i0 + 0] = m0.x ? 0.f : MASKNEG;
        Bias[i0 + 1] = m0.y ? 0.f : MASKNEG;
        Bias[i0 + 2] = m0.z ? 0.f : MASKNEG;
        Bias[i0 + 3] = m0.w ? 0.f : MASKNEG;
        Bias[i0 + 4] = m1.x ? 0.f : MASKNEG;
        Bias[i0 + 5] = m1.y ? 0.f : MASKNEG;
        Bias[i0 + 6] = m1.z ? 0.f : MASKNEG;
        Bias[i0 + 7] = m1.w ? 0.f : MASKNEG;
    }

    // Q fragments (B-operand: lane -> Q[q=c, k=ks*32+g*8+j]); pre-scaled.
    f16x8 qf[2][2];
    #pragma unroll
    for (int ks = 0; ks < 2; ++ks) {
        qf[0][ks] = *(const f16x8*)
            &Qws[(size_t)(b * 2048 + qlo + c) * 512 + h * 64 + ks * 32 + g * 8];
        qf[1][ks] = *(const f16x8*)
            &Qws[(size_t)(b * 2048 + qhi + c) * 512 + h * 64 + ks * 32 + g * 8];
    }

    f32x4 o[2][4] = {};
    float mrow[2] = {-INFINITY, -INFINITY};   // per-lane row state (q = c)
    float lrow[2] = {0.f, 0.f};

    const int sr = tid >> 3, sc = tid & 7;
    const f16* Kbase = Kws + (size_t)(b * 2048) * 512 + h * 64;
    const f16* Vbase = Vt + (size_t)(n * 64) * 2048;
    float* prow0 = pre_score + ((size_t)n * 2048 + qlo + c) * 2048;
    float* prow1 = pre_score + ((size_t)n * 2048 + qhi + c) * 2048;

    const int stageEnd = 32 - qt;      // staged (any-live) tile bound

    uint4 ka0, ka1, va0, va1;          // reg staging
    auto glbload = [&](int kt) {
        ka0 = *(const uint4*)&Kbase[(size_t)(kt * 64 + sr) * 512 + sc * 8];
        ka1 = *(const uint4*)&Kbase[(size_t)(kt * 64 + sr + 32) * 512 + sc * 8];
        va0 = *(const uint4*)&Vbase[(size_t)sr * 2048 + kt * 64 + sc * 8];
        va1 = *(const uint4*)&Vbase[(size_t)(sr + 32) * 2048 + kt * 64 + sc * 8];
    };

    // softmax + PV for one chunk (mi), Pl reused between chunks.
    auto chunk_sm_pv = [&](int mi, bool bnd, const f32x4* s2c, const f32x4* bi)
        __attribute__((always_inline)) {
        float sl[4][4];
        #pragma unroll
        for (int kc = 0; kc < 4; ++kc)
            #pragma unroll
            for (int r = 0; r < 4; ++r) {
                float sv = s2c[kc][r] + bi[kc][r];
                int klocal = kc * 16 + g * 4 + r;
                sl[kc][r] = (bnd && klocal > qrel) ? MASKNEG : sv;
            }
        float rm = sl[0][0];
        #pragma unroll
        for (int kc = 0; kc < 4; ++kc)
            #pragma unroll
            for (int r = 0; r < 4; ++r) rm = fmaxf(rm, sl[kc][r]);
        rm = fmaxf(rm, __shfl_xor(rm, 16, 64));
        rm = fmaxf(rm, __shfl_xor(rm, 32, 64));
        float mn = fmaxf(mrow[mi], rm);
        float alpha = exp2f((mrow[mi] - mn) * LOG2E);
        mrow[mi] = mn;
        float ml2 = mn * LOG2E;
        float rs = 0.f;
        #pragma unroll
        for (int kc = 0; kc < 4; ++kc) {
            f16x4 pk;
            #pragma unroll
            for (int r = 0; r < 4; ++r) {
                float pe = exp2f(fmaf(sl[kc][r], LOG2E, -ml2));
                rs += pe;
                pk[r] = (f16)pe;
            }
            *(f16x4*)&Pl[wid][c * 72 + kc * 16 + g * 4] = pk;
        }
        rs += __shfl_xor(rs, 16, 64);
        rs += __shfl_xor(rs, 32, 64);
        lrow[mi] = lrow[mi] * alpha + rs;
        #pragma unroll
        for (int r = 0; r < 4; ++r) {
            float af = __shfl(alpha, g * 4 + r, 64);
            #pragma unroll
            for (int dn = 0; dn < 4; ++dn) o[mi][dn][r] *= af;
        }
        asm volatile("s_waitcnt lgkmcnt(0)" ::: "memory");   // Pl write->read
        #pragma unroll
        for (int ks = 0; ks < 2; ++ks) {
            f16x8 pa = *(const f16x8*)&Pl[wid][c * 72 + ks * 32 + g * 8];
            #pragma unroll
            for (int dn = 0; dn < 4; ++dn) {
                f16x8 vb = *(const f16x8*)&Vl[(dn * 16 + c) * 72 + ks * 32 + g * 8];
                o[mi][dn] = MFMA16(pa, vb, o[mi][dn]);
            }
        }
    };

    glbload(p);
    for (int kt = p; kt < stageEnd; kt += 2) {
        asm volatile("s_waitcnt lgkmcnt(0)" ::: "memory");
        __builtin_amdgcn_s_barrier();
        *(uint4*)&Kl[sr * 72 + sc * 8]        = ka0;
        *(uint4*)&Kl[(sr + 32) * 72 + sc * 8] = ka1;
        *(uint4*)&Vl[sr * 72 + sc * 8]        = va0;
        *(uint4*)&Vl[(sr + 32) * 72 + sc * 8] = va1;
        asm volatile("s_waitcnt lgkmcnt(0)" ::: "memory");
        __builtin_amdgcn_s_barrier();
        if (kt + 2 < stageEnd) glbload(kt + 2);   // BEFORE stores

        // ---- S = K Q^T (swapped): lane (g,c) -> k=kc*16+g*4+r, q=c --------
        f32x4 s2[2][4] = {};
        #pragma unroll
        for (int kc = 0; kc < 4; ++kc)
            #pragma unroll
            for (int ks = 0; ks < 2; ++ks) {
                f16x8 kf = *(const f16x8*)&Kl[(kc * 16 + c) * 72 + ks * 32 + g * 8];
                s2[0][kc] = MFMA16(kf, qf[0][ks], s2[0][kc]);
                s2[1][kc] = MFMA16(kf, qf[1][ks], s2[1][kc]);
            }

        // ---- pre_score stores -------------------------------------------
        #pragma unroll
        for (int kc = 0; kc < 4; ++kc) {
            *(f32x4*)&prow0[kt * 64 + kc * 16 + g * 4] = s2[0][kc];
            *(f32x4*)&prow1[kt * 64 + kc * 16 + g * 4] = s2[1][kc];
        }

        f32x4 bi[4];
        #pragma unroll
        for (int kc = 0; kc < 4; ++kc)
            bi[kc] = *(const f32x4*)&Bias[kt * 64 + kc * 16 + g * 4];

        const bool L0 = (kt <= qt);
        if (L0) chunk_sm_pv(0, kt == qt, s2[0], bi);
        asm volatile("s_waitcnt lgkmcnt(0)" ::: "memory");   // lo PV reads done
        chunk_sm_pv(1, kt == 31 - qt, s2[1], bi);            // hi always live
    }

    // ---- dead tiles (this parity): barrier-free score-only ----------------
    for (int kt = stageEnd + ((stageEnd ^ p) & 1); kt < 32; kt += 2) {
        f32x4 s2[2][4] = {};
        #pragma unroll
        for (int kc = 0; kc < 4; ++kc)
            #pragma unroll
            for (int ks = 0; ks < 2; ++ks) {
                f16x8 kf = *(const f16x8*)
                    &Kbase[(size_t)(kt * 64 + kc * 16 + c) * 512 + ks * 32 + g * 8];
                s2[0][kc] = MFMA16(kf, qf[0][ks], s2[0][kc]);
                s2[1][kc] = MFMA16(kf, qf[1][ks], s2[1][kc]);
            }
        #pragma unroll
        for (int kc = 0; kc < 4; ++kc) {
            *(f32x4*)&prow0[kt * 64 + kc * 16 + g * 4] = s2[0][kc];
            *(f32x4*)&prow1[kt * 64 + kc * 16 + g * 4] = s2[1][kc];
        }
    }

    // ---- epilogue: store partials (m, l, unnormalized o) ------------------
    f16* pb = part + (size_t)p * 65536 * 72;
    #pragma unroll
    for (int mi = 0; mi < 2; ++mi) {
        size_t rowbase = (size_t)n * 2048 + (mi ? qhi : qlo);
        #pragma unroll
        for (int r = 0; r < 4; ++r)
            #pragma unroll
            for (int dn = 0; dn < 4; ++dn)
                pb[(rowbase + g * 4 + r) * 72 + dn * 16 + c] = (f16)o[mi][dn][r];
        if (g == 0) {
            float* pf = (float*)&pb[(rowbase + c) * 72 + 64];
            pf[0] = mrow[mi];
            pf[1] = lrow[mi];
        }
    }
}

// ---------------------------------------------------------------------------
// Kernel 2b: merge the two parity partials -> heads f16 [b*2048+s][h*64+d].
// Thread: one (row, 16-d group).  Fully-masked rows -> Vsum/2048.
// ---------------------------------------------------------------------------
__global__ __launch_bounds__(256) void combine_kernel(
    const f16* __restrict__ part, const float* __restrict__ Vsum,
    f16* __restrict__ Aat)
{
    const int t  = threadIdx.x;
    const int R  = blockIdx.x * 64 + (t >> 2);   // global row id = n*2048+q
    const int dg = (t & 3) * 16;
    const int n = R >> 11, q = R & 2047;
    const int h = n >> 2, b = n & 3;
    const f16* p0 = part + (size_t)R * 72;
    const f16* p1 = part + ((size_t)65536 + R) * 72;
    const float* ml0 = (const float*)(p0 + 64);
    const float* ml1 = (const float*)(p1 + 64);
    float m0 = ml0[0], l0 = ml0[1];
    float m1 = ml1[0], l1 = ml1[1];
    float m = fmaxf(m0, m1);
    f16* outp = Aat + ((size_t)(b * 2048 + q)) * 512 + h * 64 + dg;
    f16x8 r0, r1;
    if (m < DEADTHR) {
        const float* vs = Vsum + n * 64 + dg;
        #pragma unroll
        for (int i = 0; i < 8; ++i) {
            r0[i] = (f16)(vs[i] * (1.0f / 2048.0f));
            r1[i] = (f16)(vs[8 + i] * (1.0f / 2048.0f));
        }
    } else {
        float w0 = (m0 < DEADTHR) ? 0.f : exp2f((m0 - m) * LOG2E);
        float w1 = (m1 < DEADTHR) ? 0.f : exp2f((m1 - m) * LOG2E);
        float invl = 1.0f / (l0 * w0 + l1 * w1);
        f16x8 a0 = *(const f16x8*)&p0[dg];
        f16x8 a1 = *(const f16x8*)&p0[dg + 8];
        f16x8 c0 = *(const f16x8*)&p1[dg];
        f16x8 c1 = *(const f16x8*)&p1[dg + 8];
        #pragma unroll
        for (int i = 0; i < 8; ++i) {
            r0[i] = (f16)(((float)a0[i] * w0 + (float)c0[i] * w1) * invl);
            r1[i] = (f16)(((float)a1[i] * w0 + (float)c1[i] * w1) * invl);
        }
    }
    *(f16x8*)outp = r0;
    *(f16x8*)(outp + 8) = r1;
}

// ---------------------------------------------------------------------------
// Kernel 3: output projection.
// ---------------------------------------------------------------------------
__global__ __launch_bounds__(256) void out_gemm(
    const f16* __restrict__ Aattn, const float* __restrict__ Wo,
    const float* __restrict__ bo, float* __restrict__ outp)
{
    __shared__ f16 Al[128 * 48];
    __shared__ f16 Wl[64 * 48];

    const int tid = threadIdx.x;
    const int n0 = blockIdx.x * 64;
    const int m0 = blockIdx.y * 128;
    const int wid = tid >> 6, lane = tid & 63;
    const int g = lane >> 4, c = lane & 15;
    const int wm = (wid >> 1) * 64, wn = (wid & 1) * 32;

    const int sr4 = tid >> 2, sc4 = tid & 3;
    const int sr8 = tid >> 3, sc8 = tid & 7;

    f32x4 acc[4][2] = {};

    for (int kk = 0; kk < 512; kk += 32) {
        __syncthreads();
        #pragma unroll
        for (int rr = 0; rr < 2; ++rr) {
            int row = sr4 + rr * 64;
            *(uint4*)&Al[row * 48 + sc4 * 8] =
                *(const uint4*)&Aattn[(size_t)(m0 + row) * 512 + kk + sc4 * 8];
        }
        #pragma unroll
        for (int rr = 0; rr < 2; ++rr) {
            int row = sr8 + rr * 32;
            float4 v = *(const float4*)&Wo[(size_t)(n0 + row) * 512 + kk + sc8 * 4];
            f16x4 h4 = {(f16)v.x, (f16)v.y, (f16)v.z, (f16)v.w};
            *(f16x4*)&Wl[row * 48 + sc8 * 4] = h4;
        }
        __syncthreads();

        f16x8 b0 = *(const f16x8*)&Wl[(wn +  0 + c) * 48 + g * 8];
        f16x8 b1 = *(const f16x8*)&Wl[(wn + 16 + c) * 48 + g * 8];
        #pragma unroll
        for (int mf = 0; mf < 4; ++mf) {
            f16x8 a = *(const f16x8*)&Al[(wm + mf * 16 + c) * 48 + g * 8];
            acc[mf][0] = MFMA16(a, b0, acc[mf][0]);
            acc[mf][1] = MFMA16(a, b1, acc[mf][1]);
        }
    }

    #pragma unroll
    for (int nf = 0; nf < 2; ++nf) {
        int cc = n0 + wn + nf * 16 + c;
        float bval = bo[cc];
        #pragma unroll
        for (int mf = 0; mf < 4; ++mf)
            #pragma unroll
            for (int r = 0; r < 4; ++r)
                outp[(size_t)(m0 + wm + mf * 16 + g * 4 + r) * 512 + cc] =
                    acc[mf][nf][r] + bval;
    }
}

// ---------------------------------------------------------------------------
extern "C" void kernel_launch(void* const* d_in, const int* in_sizes, int n_in,
                              void* d_out, int out_size, void* d_ws, size_t ws_size,
                              hipStream_t stream)
{
    (void)in_sizes; (void)n_in; (void)out_size; (void)ws_size;

    const float* x  = (const float*)d_in[0];
    const int*   pm = (const int*)  d_in[1];
    const float* Wq = (const float*)d_in[2];
    const float* bq = (const float*)d_in[3];
    const float* Wk = (const float*)d_in[4];
    const float* bk = (const float*)d_in[5];
    const float* Wv = (const float*)d_in[6];
    const float* bv = (const float*)d_in[7];
    const float* Wo = (const float*)d_in[8];
    const float* bo = (const float*)d_in[9];

    float* out = (float*)d_out;                 // [4][2048][512]
    float* pre = out + (size_t)4 * 2048 * 512;  // [32][2048][2048]

    f16*   Qws  = (f16*)d_ws;                   //  8 MiB (pre-scaled by 1/8)
    f16*   Kws  = Qws + (size_t)8192 * 512;     //  8 MiB
    f16*   Vt   = Kws + (size_t)8192 * 512;     //  8 MiB (transposed V)
    f16*   Aat  = Vt  + (size_t)2048 * 2048;    //  8 MiB (heads)
    float* Vsum = (float*)(Aat + (size_t)8192 * 512);  // 8 KiB
    f16*   part = (f16*)(Vsum + 2048);          // 2 x 65536 rows x 144B ~ 18.9 MiB

    qkv_gemm   <<<dim3(24, 64), 256, 0, stream>>>(x, Wq, bq, Wk, bk, Wv, bv, Qws, Kws, Vt);
    vsum_kernel<<<dim3(512),    256, 0, stream>>>(Vt, Vsum);
    attn_kernel<<<dim3(16, 32, 2), 256, 0, stream>>>(Qws, Kws, Vt, pm, pre, part);
    combine_kernel<<<dim3(1024), 256, 0, stream>>>(part, Vsum, Aat);
    out_gemm   <<<dim3(8, 64),  256, 0, stream>>>(Aat, Wo, bo, out);
}